// Round 10
// baseline (1893.371 us; speedup 1.0000x reference)
//
#include <hip/hip_runtime.h>
#include <hip/hip_bf16.h>
#include <math.h>

#define B_ 4
#define N_ 4096
#define K_ 20
#define NK_ (N_*K_)   // 81920
#define G_ 16
#define EPS_ 1e-5f
#define NBLK_ (NK_/256)   // 320 column-blocks per batch

typedef __hip_bfloat16 bf16;
__device__ inline float b2f(bf16 v) { return __bfloat162float(v); }
__device__ inline bf16  f2b(float v){ return __float2bfloat16(v); }

// ---------------- kNN: bit-exact np pdist (no FMA, sequential adds) ----------------
__global__ __launch_bounds__(256) void knn_kernel(const float* __restrict__ pts, int* __restrict__ idx)
{
    __shared__ float pd[N_];
    __shared__ float rbv[4];
    __shared__ int   rbi[4];
    int bid = blockIdx.x;
    int b = bid >> 12, i = bid & (N_ - 1);
    const float* pb = pts + (size_t)b * 6 * N_;
    int t = threadIdx.x;
    float xi = pb[i], yi = pb[N_ + i], zi = pb[2 * N_ + i];
    float xxi = __fadd_rn(__fadd_rn(__fmul_rn(xi, xi), __fmul_rn(yi, yi)), __fmul_rn(zi, zi));
    float nxxi = -xxi;
    for (int j = t; j < N_; j += 256) {
        float xj = pb[j], yj = pb[N_ + j], zj = pb[2 * N_ + j];
        float xxj = __fadd_rn(__fadd_rn(__fmul_rn(xj, xj), __fmul_rn(yj, yj)), __fmul_rn(zj, zj));
        float px = __fmul_rn(xi, xj);
        float py = __fmul_rn(yi, yj);
        float pz = __fmul_rn(zi, zj);
        float dot = __fadd_rn(__fadd_rn(px, py), pz);
        float inner = __fmul_rn(-2.0f, dot);
        pd[j] = __fsub_rn(__fsub_rn(nxxi, inner), xxj);
    }
    __syncthreads();
    for (int it = 0; it < K_; ++it) {
        float best = -INFINITY; int bj = -1;
        for (int j = t; j < N_; j += 256) {
            float v = pd[j];
            if (v > best || (v == best && j > bj)) { best = v; bj = j; }
        }
        for (int off = 32; off > 0; off >>= 1) {
            float ov = __shfl_down(best, off);
            int   oj = __shfl_down(bj, off);
            if (ov > best || (ov == best && oj > bj)) { best = ov; bj = oj; }
        }
        if ((t & 63) == 0) { rbv[t >> 6] = best; rbi[t >> 6] = bj; }
        __syncthreads();
        if (t == 0) {
            float bv = rbv[0]; int bi = rbi[0];
            for (int w = 1; w < 4; ++w)
                if (rbv[w] > bv || (rbv[w] == bv && rbi[w] > bi)) { bv = rbv[w]; bi = rbi[w]; }
            idx[(size_t)b * NK_ + it * N_ + i] = bi;
            pd[bi] = -INFINITY;
        }
        __syncthreads();
    }
}

// ---------------- angle with "x < 0" quadrant predicate (non-IEEE at (0,-0)) ----------------
// Models the common atan2 lowering: correction applied only when d < 0 STRICTLY,
// so arctan2(+0, -0) -> 0 (IEEE would give pi). Probe for the reference's behavior
// at the degenerate self-neighbor slots (lxyz = +0 vector).
__device__ inline float angle3(float ax, float ay, float az, float bx, float by, float bz)
{
    float cx = __fsub_rn(__fmul_rn(ay, bz), __fmul_rn(az, by));
    float cy = __fsub_rn(__fmul_rn(az, bx), __fmul_rn(ax, bz));
    float cz = __fsub_rn(__fmul_rn(ax, by), __fmul_rn(ay, bx));
    float cn = sqrtf(__fadd_rn(__fadd_rn(__fmul_rn(cx, cx), __fmul_rn(cy, cy)), __fmul_rn(cz, cz)));
    float d  = __fadd_rn(__fadd_rn(__fmul_rn(ax, bx), __fmul_rn(ay, by)), __fmul_rn(az, bz));
    if (cn == 0.0f)
        return (d < 0.0f) ? 3.14159274101257324e+00f : 0.0f;   // -0 -> 0 (probe)
    return atan2f(cn, d);
}

__global__ __launch_bounds__(256) void feature_kernel(const float* __restrict__ pts,
                                                      const int* __restrict__ idx,
                                                      float* __restrict__ x0)
{
    int t = blockIdx.x * 256 + threadIdx.x;           // [0, B*NK)
    int col = t % NK_;
    int b = t / NK_;
    int n = col & (N_ - 1);
    int j = idx[t];
    const float* pb = pts + (size_t)b * 6 * N_;
    float cx = pb[n],            cy = pb[N_ + n],     cz = pb[2 * N_ + n];
    float gx = pb[j],            gy = pb[N_ + j],     gz = pb[2 * N_ + j];
    float rx = pb[3 * N_ + n],   ry = pb[4 * N_ + n], rz = pb[5 * N_ + n];
    float ix = pb[3 * N_ + j],   iy = pb[4 * N_ + j], iz = pb[5 * N_ + j];
    float lx = __fsub_rn(gx, cx), ly = __fsub_rn(gy, cy), lz = __fsub_rn(gz, cz);

    float f9  = angle3(rx, ry, rz, lx, ly, lz);
    float f10 = angle3(ix, iy, iz, lx, ly, lz);
    float f11 = angle3(rx, ry, rz, ix, iy, iz);
    float f12 = sqrtf(__fadd_rn(__fadd_rn(__fmul_rn(lx, lx), __fmul_rn(ly, ly)), __fmul_rn(lz, lz)));

    float* xp = x0 + (size_t)b * 13 * NK_ + col;
    xp[0  * (size_t)NK_] = gx;
    xp[1  * (size_t)NK_] = gy;
    xp[2  * (size_t)NK_] = gz;
    xp[3  * (size_t)NK_] = cx;
    xp[4  * (size_t)NK_] = cy;
    xp[5  * (size_t)NK_] = cz;
    xp[6  * (size_t)NK_] = lx;
    xp[7  * (size_t)NK_] = ly;
    xp[8  * (size_t)NK_] = lz;
    xp[9  * (size_t)NK_] = f9;
    xp[10 * (size_t)NK_] = f10;
    xp[11 * (size_t)NK_] = f11;
    xp[12 * (size_t)NK_] = f12;
}

// ---------------- deterministic block reduction: 16 sums + 16 sumsqs -> 32 partials ----------------
__device__ inline void block_reduce_write(const float gsum[16], const float gsq[16], float* __restrict__ dst)
{
    __shared__ float red[4][32];
    int t = threadIdx.x, lane = t & 63, w = t >> 6;
    #pragma unroll
    for (int r = 0; r < 16; ++r) {
        float v = gsum[r];
        #pragma unroll
        for (int off = 32; off > 0; off >>= 1) v += __shfl_down(v, off);
        if (lane == 0) red[w][r] = v;
        float q = gsq[r];
        #pragma unroll
        for (int off = 32; off > 0; off >>= 1) q += __shfl_down(q, off);
        if (lane == 0) red[w][16 + r] = q;
    }
    __syncthreads();
    if (t < 32) dst[t] = red[0][t] + red[1][t] + red[2][t] + red[3][t];
}

// ---------------- stage1: conv1 -> GN1 partial stats (y1 never stored) ----------------
__global__ __launch_bounds__(256) void stage1_kernel(const float* __restrict__ x0,
    const float* __restrict__ W1, float* __restrict__ p1)
{
    int b = blockIdx.y;
    int col = blockIdx.x * 256 + threadIdx.x;
    const float* xb = x0 + (size_t)b * 13 * NK_ + col;
    float xr[13];
    #pragma unroll
    for (int c = 0; c < 13; ++c) xr[c] = xb[(size_t)c * NK_];
    float gsum[16], gsq[16];
    #pragma unroll
    for (int g = 0; g < 16; ++g) {
        float sg = 0.f, qg = 0.f;
        for (int oi = 0; oi < 4; ++oi) {
            int o = g * 4 + oi;
            float acc = 0.f;
            #pragma unroll
            for (int c = 0; c < 13; ++c) acc = fmaf(W1[o * 13 + c], xr[c], acc);
            sg += acc; qg += acc * acc;
        }
        gsum[g] = sg; gsq[g] = qg;
    }
    block_reduce_write(gsum, gsq, p1 + ((size_t)b * NBLK_ + blockIdx.x) * 32);
}

// ---------------- stage2: conv1+GN1+relu+conv2 -> GN2 partial stats (y2 never stored) ----------------
__global__ __launch_bounds__(256) void stage2_kernel(const float* __restrict__ x0,
    const float* __restrict__ W1, const float* __restrict__ a1, const float* __restrict__ s1,
    const float* __restrict__ W2, float* __restrict__ p2)
{
    __shared__ float aL[64], sL[64];
    int b = blockIdx.y;
    int col = blockIdx.x * 256 + threadIdx.x;
    if (threadIdx.x < 64) {
        aL[threadIdx.x] = a1[b * 64 + threadIdx.x];
        sL[threadIdx.x] = s1[b * 64 + threadIdx.x];
    }
    __syncthreads();
    const float* xb = x0 + (size_t)b * 13 * NK_ + col;
    float xr[13];
    #pragma unroll
    for (int c = 0; c < 13; ++c) xr[c] = xb[(size_t)c * NK_];
    float y1r[64];
    #pragma unroll
    for (int o = 0; o < 64; ++o) {
        float acc = 0.f;
        #pragma unroll
        for (int c = 0; c < 13; ++c) acc = fmaf(W1[o * 13 + c], xr[c], acc);
        y1r[o] = fmaxf(fmaf(acc, aL[o], sL[o]), 0.f);
    }
    float gsum[16], gsq[16];
    #pragma unroll
    for (int g = 0; g < 16; ++g) {
        float sg = 0.f, qg = 0.f;
        for (int oi = 0; oi < 4; ++oi) {
            int o = g * 4 + oi;
            float acc = 0.f;
            #pragma unroll
            for (int c = 0; c < 64; ++c) acc = fmaf(W2[o * 64 + c], y1r[c], acc);
            sg += acc; qg += acc * acc;
        }
        gsum[g] = sg; gsq[g] = qg;
    }
    block_reduce_write(gsum, gsq, p2 + ((size_t)b * NBLK_ + blockIdx.x) * 32);
}

// ---------------- stage3: chain conv1..conv3 -> y3 (bf16) + GN3 stats (pre-rounding) ----------------
__global__ __launch_bounds__(256) void stage3_kernel(const float* __restrict__ x0,
    const float* __restrict__ W1, const float* __restrict__ a1, const float* __restrict__ s1,
    const float* __restrict__ W2, const float* __restrict__ a2, const float* __restrict__ s2,
    const float* __restrict__ W3, bf16* __restrict__ y3, float* __restrict__ p3)
{
    __shared__ float a1L[64], s1L[64], a2L[64], s2L[64];
    int b = blockIdx.y;
    int col = blockIdx.x * 256 + threadIdx.x;
    if (threadIdx.x < 64) {
        a1L[threadIdx.x] = a1[b * 64 + threadIdx.x];
        s1L[threadIdx.x] = s1[b * 64 + threadIdx.x];
        a2L[threadIdx.x] = a2[b * 64 + threadIdx.x];
        s2L[threadIdx.x] = s2[b * 64 + threadIdx.x];
    }
    __syncthreads();
    const float* xb = x0 + (size_t)b * 13 * NK_ + col;
    float xr[13];
    #pragma unroll
    for (int c = 0; c < 13; ++c) xr[c] = xb[(size_t)c * NK_];
    float y1r[64];
    #pragma unroll
    for (int o = 0; o < 64; ++o) {
        float acc = 0.f;
        #pragma unroll
        for (int c = 0; c < 13; ++c) acc = fmaf(W1[o * 13 + c], xr[c], acc);
        y1r[o] = fmaxf(fmaf(acc, a1L[o], s1L[o]), 0.f);
    }
    float y2r[64];
    #pragma unroll
    for (int o = 0; o < 64; ++o) {
        float acc = 0.f;
        #pragma unroll
        for (int c = 0; c < 64; ++c) acc = fmaf(W2[o * 64 + c], y1r[c], acc);
        y2r[o] = fmaxf(fmaf(acc, a2L[o], s2L[o]), 0.f);
    }
    bf16* yb = y3 + (size_t)b * 128 * NK_ + col;
    float gsum[16], gsq[16];
    #pragma unroll
    for (int g = 0; g < 16; ++g) {
        float sg = 0.f, qg = 0.f;
        for (int oi = 0; oi < 8; ++oi) {
            int o = g * 8 + oi;
            float acc = 0.f;
            #pragma unroll
            for (int c = 0; c < 64; ++c) acc = fmaf(W3[o * 64 + c], y2r[c], acc);
            yb[(size_t)o * NK_] = f2b(acc);
            sg += acc; qg += acc * acc;
        }
        gsum[g] = sg; gsq[g] = qg;
    }
    block_reduce_write(gsum, gsq, p3 + ((size_t)b * NBLK_ + blockIdx.x) * 32);
}

// ---------------- fold GN into per-(b,c) scale/shift from block partials ----------------
template<int COUT>
__global__ __launch_bounds__(256) void finalize_kernel(const float* __restrict__ part,
    const float* __restrict__ gamma, const float* __restrict__ beta,
    float* __restrict__ ga, float* __restrict__ sh)
{
    int t = blockIdx.x * 256 + threadIdx.x;
    if (t >= B_ * COUT) return;
    int b = t / COUT, c = t % COUT;
    int g = c / (COUT / G_);
    float sum = 0.f, sq = 0.f;
    for (int blk = 0; blk < NBLK_; ++blk) {
        sum += part[((size_t)b * NBLK_ + blk) * 32 + g];
        sq  += part[((size_t)b * NBLK_ + blk) * 32 + 16 + g];
    }
    float cnt = (float)(COUT / G_) * (float)NK_;
    float mean = sum / cnt;
    float var = fmaxf(sq / cnt - mean * mean, 0.f);
    float sc = gamma[c] * rsqrtf(var + EPS_);
    ga[t] = sc;
    sh[t] = beta[c] - mean * sc;
}

// ---------------- conv4 fused: conv + max over k + deterministic GN4 partials ----------------
template<int OC4>
__global__ __launch_bounds__(256) void conv4_fused_kernel(
    const bf16* __restrict__ y3, const float* __restrict__ W4,
    const float* __restrict__ a3, const float* __restrict__ s3,
    float* __restrict__ m4, float* __restrict__ part)
{
    __shared__ float aL[128], sL[128];
    __shared__ float red[256];
    int nx = blockIdx.x, oy = blockIdx.y, b = blockIdx.z;
    int n = nx * 256 + threadIdx.x;
    int o0 = oy * OC4;
    for (int c = threadIdx.x; c < 128; c += 256) {
        aL[c] = a3[b * 128 + c];
        sL[c] = s3[b * 128 + c];
    }
    __syncthreads();
    const bf16* xb = y3 + (size_t)b * 128 * NK_ + n;
    float am[OC4];
    float ps0 = 0.f, pq0 = 0.f, ps1 = 0.f, pq1 = 0.f;
    #pragma unroll
    for (int o = 0; o < OC4; ++o) am[o] = -INFINITY;
    for (int k = 0; k < K_; ++k) {
        float acc[OC4];
        #pragma unroll
        for (int o = 0; o < OC4; ++o) acc[o] = 0.f;
        const bf16* xk = xb + (size_t)k * N_;
        #pragma unroll 4
        for (int c = 0; c < 128; ++c) {
            float v = fmaxf(fmaf(b2f(xk[(size_t)c * NK_]), aL[c], sL[c]), 0.f);
            #pragma unroll
            for (int o = 0; o < OC4; ++o)
                acc[o] = fmaf(W4[(o0 + o) * 128 + c], v, acc[o]);
        }
        #pragma unroll
        for (int o = 0; o < OC4; ++o) {
            float v = acc[o];
            am[o] = fmaxf(am[o], v);
            if (o < OC4 / 2) { ps0 += v; pq0 += v * v; }
            else             { ps1 += v; pq1 += v * v; }
        }
    }
    float* mb = m4 + ((size_t)b * 256 + o0) * N_ + n;
    #pragma unroll
    for (int o = 0; o < OC4; ++o) mb[(size_t)o * N_] = am[o];

    float vals[4] = { ps0, pq0, ps1, pq1 };
    #pragma unroll
    for (int r = 0; r < 4; ++r) {
        red[threadIdx.x] = vals[r];
        __syncthreads();
        for (int h = 128; h > 0; h >>= 1) {
            if (threadIdx.x < h) red[threadIdx.x] += red[threadIdx.x + h];
            __syncthreads();
        }
        if (threadIdx.x == 0) {
            int gl = r >> 1, which = r & 1;
            part[((((b * 8 + oy) * 2 + gl) * 2) + which) * 16 + nx] = red[0];
        }
        __syncthreads();
    }
}

// ---------------- GN4 finalize from deterministic partials ----------------
__global__ __launch_bounds__(256) void finalize4_kernel(const float* __restrict__ part,
    const float* __restrict__ gamma, const float* __restrict__ beta,
    float* __restrict__ ga, float* __restrict__ sh)
{
    int t = blockIdx.x * 256 + threadIdx.x;   // B*256
    if (t >= B_ * 256) return;
    int b = t >> 8, c = t & 255;
    int g = c >> 4, oy = g >> 1, gl = g & 1;
    float sum = 0.f, sq = 0.f;
    for (int nx = 0; nx < 16; ++nx) {
        sum += part[((((b * 8 + oy) * 2 + gl) * 2) + 0) * 16 + nx];
        sq  += part[((((b * 8 + oy) * 2 + gl) * 2) + 1) * 16 + nx];
    }
    float cnt = 16.f * (float)NK_;
    float mean = sum / cnt;
    float var = fmaxf(sq / cnt - mean * mean, 0.f);
    float sc = gamma[c] * rsqrtf(var + EPS_);
    ga[t] = sc;
    sh[t] = beta[c] - mean * sc;
}

// ---------------- final: out = relu(a*max_k + s)  (valid since a>0) ----------------
__global__ __launch_bounds__(256) void apply_kernel(const float* __restrict__ m4,
    const float* __restrict__ ga, const float* __restrict__ sh, float* __restrict__ out)
{
    int t = blockIdx.x * 256 + threadIdx.x;   // b*256*N + c*N + n
    int bc = t >> 12;
    out[t] = fmaxf(fmaf(m4[t], ga[bc], sh[bc]), 0.f);
}

extern "C" void kernel_launch(void* const* d_in, const int* in_sizes, int n_in,
                              void* d_out, int out_size, void* d_ws, size_t ws_size,
                              hipStream_t stream)
{
    const float* pts = (const float*)d_in[0];
    const float* W1 = (const float*)d_in[1];
    const float* g1 = (const float*)d_in[2];
    const float* bt1 = (const float*)d_in[3];
    const float* W2 = (const float*)d_in[4];
    const float* g2 = (const float*)d_in[5];
    const float* bt2 = (const float*)d_in[6];
    const float* W3 = (const float*)d_in[7];
    const float* g3 = (const float*)d_in[8];
    const float* bt3 = (const float*)d_in[9];
    const float* W4 = (const float*)d_in[10];
    const float* g4 = (const float*)d_in[11];
    const float* bt4 = (const float*)d_in[12];
    float* out = (float*)d_out;

    char* ws = (char*)d_ws;
    size_t off = 0;
    auto alloc = [&](size_t bytes) -> void* {
        void* p = ws + off;
        off = (off + bytes + 255) & ~(size_t)255;
        return p;
    };
    int*   idx  = (int*)  alloc((size_t)B_ * NK_ * 4);           // 1.3 MB
    float* x0   = (float*)alloc((size_t)B_ * 13 * NK_ * 4);      // 17 MB
    bf16*  y3   = (bf16*) alloc((size_t)B_ * 128 * NK_ * 2);     // 84 MB
    float* m4   = (float*)alloc((size_t)B_ * 256 * N_ * 4);      // 16.8 MB
    float* p1   = (float*)alloc((size_t)B_ * NBLK_ * 32 * 4);    // 164 KB
    float* p2   = (float*)alloc((size_t)B_ * NBLK_ * 32 * 4);
    float* p3   = (float*)alloc((size_t)B_ * NBLK_ * 32 * 4);
    float* part4= (float*)alloc(2048 * 4);
    float* a1 = (float*)alloc(B_ * 64 * 4);
    float* s1 = (float*)alloc(B_ * 64 * 4);
    float* a2 = (float*)alloc(B_ * 64 * 4);
    float* s2 = (float*)alloc(B_ * 64 * 4);
    float* a3 = (float*)alloc(B_ * 128 * 4);
    float* s3 = (float*)alloc(B_ * 128 * 4);
    float* a4 = (float*)alloc(B_ * 256 * 4);
    float* s4 = (float*)alloc(B_ * 256 * 4);
    (void)ws_size; (void)in_sizes; (void)n_in; (void)out_size;

    knn_kernel<<<B_ * N_, 256, 0, stream>>>(pts, idx);
    feature_kernel<<<(B_ * NK_) / 256, 256, 0, stream>>>(pts, idx, x0);

    stage1_kernel<<<dim3(NBLK_, B_), 256, 0, stream>>>(x0, W1, p1);
    finalize_kernel<64><<<1, 256, 0, stream>>>(p1, g1, bt1, a1, s1);

    stage2_kernel<<<dim3(NBLK_, B_), 256, 0, stream>>>(x0, W1, a1, s1, W2, p2);
    finalize_kernel<64><<<1, 256, 0, stream>>>(p2, g2, bt2, a2, s2);

    stage3_kernel<<<dim3(NBLK_, B_), 256, 0, stream>>>(x0, W1, a1, s1, W2, a2, s2, W3, y3, p3);
    finalize_kernel<128><<<2, 256, 0, stream>>>(p3, g3, bt3, a3, s3);

    conv4_fused_kernel<32><<<dim3(N_ / 256, 8, B_), 256, 0, stream>>>(y3, W4, a3, s3, m4, part4);
    finalize4_kernel<<<4, 256, 0, stream>>>(part4, g4, bt4, a4, s4);

    apply_kernel<<<(B_ * 256 * N_) / 256, 256, 0, stream>>>(m4, a4, s4, out);
}

// Round 11
// 1360.127 us; speedup vs baseline: 1.3921x; 1.3921x over previous
//
#include <hip/hip_runtime.h>
#include <hip/hip_bf16.h>
#include <math.h>

#define B_ 4
#define N_ 4096
#define K_ 20
#define NK_ (N_*K_)   // 81920
#define G_ 16
#define EPS_ 1e-5f
#define NBLK_ (NK_/256)   // 320 column-blocks per batch

typedef __hip_bfloat16 bf16;
__device__ inline float b2f(bf16 v) { return __bfloat162float(v); }
__device__ inline bf16  f2b(float v){ return __float2bfloat16(v); }

// ---------------- kNN: bit-exact np pdist (no FMA, sequential adds) ----------------
__global__ __launch_bounds__(256) void knn_kernel(const float* __restrict__ pts, int* __restrict__ idx)
{
    __shared__ float pd[N_];
    __shared__ float rbv[4];
    __shared__ int   rbi[4];
    int bid = blockIdx.x;
    int b = bid >> 12, i = bid & (N_ - 1);
    const float* pb = pts + (size_t)b * 6 * N_;
    int t = threadIdx.x;
    float xi = pb[i], yi = pb[N_ + i], zi = pb[2 * N_ + i];
    float xxi = __fadd_rn(__fadd_rn(__fmul_rn(xi, xi), __fmul_rn(yi, yi)), __fmul_rn(zi, zi));
    float nxxi = -xxi;
    for (int j = t; j < N_; j += 256) {
        float xj = pb[j], yj = pb[N_ + j], zj = pb[2 * N_ + j];
        float xxj = __fadd_rn(__fadd_rn(__fmul_rn(xj, xj), __fmul_rn(yj, yj)), __fmul_rn(zj, zj));
        float px = __fmul_rn(xi, xj);
        float py = __fmul_rn(yi, yj);
        float pz = __fmul_rn(zi, zj);
        float dot = __fadd_rn(__fadd_rn(px, py), pz);
        float inner = __fmul_rn(-2.0f, dot);
        pd[j] = __fsub_rn(__fsub_rn(nxxi, inner), xxj);
    }
    __syncthreads();
    for (int it = 0; it < K_; ++it) {
        float best = -INFINITY; int bj = -1;
        for (int j = t; j < N_; j += 256) {
            float v = pd[j];
            if (v > best || (v == best && j > bj)) { best = v; bj = j; }
        }
        for (int off = 32; off > 0; off >>= 1) {
            float ov = __shfl_down(best, off);
            int   oj = __shfl_down(bj, off);
            if (ov > best || (ov == best && oj > bj)) { best = ov; bj = oj; }
        }
        if ((t & 63) == 0) { rbv[t >> 6] = best; rbi[t >> 6] = bj; }
        __syncthreads();
        if (t == 0) {
            float bv = rbv[0]; int bi = rbi[0];
            for (int w = 1; w < 4; ++w)
                if (rbv[w] > bv || (rbv[w] == bv && rbi[w] > bi)) { bv = rbv[w]; bi = rbi[w]; }
            idx[(size_t)b * NK_ + it * N_ + i] = bi;
            pd[bi] = -INFINITY;
        }
        __syncthreads();
    }
}

// ---------------- angle: "x<0" quadrant predicate — LOAD-BEARING (round 10) ----------------
// Reference's atan2 lowering yields 0 (not IEEE pi) at (+0, -0). The degenerate
// self-neighbor slots (lxyz = +0 vector, d = -0 for all-negative normals) hit this.
__device__ inline float angle3(float ax, float ay, float az, float bx, float by, float bz)
{
    float cx = __fsub_rn(__fmul_rn(ay, bz), __fmul_rn(az, by));
    float cy = __fsub_rn(__fmul_rn(az, bx), __fmul_rn(ax, bz));
    float cz = __fsub_rn(__fmul_rn(ax, by), __fmul_rn(ay, bx));
    float cn = sqrtf(__fadd_rn(__fadd_rn(__fmul_rn(cx, cx), __fmul_rn(cy, cy)), __fmul_rn(cz, cz)));
    float d  = __fadd_rn(__fadd_rn(__fmul_rn(ax, bx), __fmul_rn(ay, by)), __fmul_rn(az, bz));
    if (cn == 0.0f)
        return (d < 0.0f) ? 3.14159274101257324e+00f : 0.0f;   // -0 -> 0
    return atan2f(cn, d);
}

__global__ __launch_bounds__(256) void feature_kernel(const float* __restrict__ pts,
                                                      const int* __restrict__ idx,
                                                      float* __restrict__ x0)
{
    int t = blockIdx.x * 256 + threadIdx.x;           // [0, B*NK)
    int col = t % NK_;
    int b = t / NK_;
    int n = col & (N_ - 1);
    int j = idx[t];
    const float* pb = pts + (size_t)b * 6 * N_;
    float cx = pb[n],            cy = pb[N_ + n],     cz = pb[2 * N_ + n];
    float gx = pb[j],            gy = pb[N_ + j],     gz = pb[2 * N_ + j];
    float rx = pb[3 * N_ + n],   ry = pb[4 * N_ + n], rz = pb[5 * N_ + n];
    float ix = pb[3 * N_ + j],   iy = pb[4 * N_ + j], iz = pb[5 * N_ + j];
    float lx = __fsub_rn(gx, cx), ly = __fsub_rn(gy, cy), lz = __fsub_rn(gz, cz);

    float f9  = angle3(rx, ry, rz, lx, ly, lz);
    float f10 = angle3(ix, iy, iz, lx, ly, lz);
    float f11 = angle3(rx, ry, rz, ix, iy, iz);
    float f12 = sqrtf(__fadd_rn(__fadd_rn(__fmul_rn(lx, lx), __fmul_rn(ly, ly)), __fmul_rn(lz, lz)));

    float* xp = x0 + (size_t)b * 13 * NK_ + col;
    xp[0  * (size_t)NK_] = gx;
    xp[1  * (size_t)NK_] = gy;
    xp[2  * (size_t)NK_] = gz;
    xp[3  * (size_t)NK_] = cx;
    xp[4  * (size_t)NK_] = cy;
    xp[5  * (size_t)NK_] = cz;
    xp[6  * (size_t)NK_] = lx;
    xp[7  * (size_t)NK_] = ly;
    xp[8  * (size_t)NK_] = lz;
    xp[9  * (size_t)NK_] = f9;
    xp[10 * (size_t)NK_] = f10;
    xp[11 * (size_t)NK_] = f11;
    xp[12 * (size_t)NK_] = f12;
}

// ---------------- deterministic block reduction: 16 sums + 16 sumsqs -> 32 partials ----------------
__device__ inline void block_reduce_write(const float gsum[16], const float gsq[16], float* __restrict__ dst)
{
    __shared__ float red[4][32];
    int t = threadIdx.x, lane = t & 63, w = t >> 6;
    #pragma unroll
    for (int r = 0; r < 16; ++r) {
        float v = gsum[r];
        #pragma unroll
        for (int off = 32; off > 0; off >>= 1) v += __shfl_down(v, off);
        if (lane == 0) red[w][r] = v;
        float q = gsq[r];
        #pragma unroll
        for (int off = 32; off > 0; off >>= 1) q += __shfl_down(q, off);
        if (lane == 0) red[w][16 + r] = q;
    }
    __syncthreads();
    if (t < 32) dst[t] = red[0][t] + red[1][t] + red[2][t] + red[3][t];
}

// ---------------- stage1: conv1 -> GN1 partial stats (y1 never stored) ----------------
__global__ __launch_bounds__(256) void stage1_kernel(const float* __restrict__ x0,
    const float* __restrict__ W1, float* __restrict__ p1)
{
    int b = blockIdx.y;
    int col = blockIdx.x * 256 + threadIdx.x;
    const float* xb = x0 + (size_t)b * 13 * NK_ + col;
    float xr[13];
    #pragma unroll
    for (int c = 0; c < 13; ++c) xr[c] = xb[(size_t)c * NK_];
    float gsum[16], gsq[16];
    #pragma unroll
    for (int g = 0; g < 16; ++g) {
        float sg = 0.f, qg = 0.f;
        for (int oi = 0; oi < 4; ++oi) {
            int o = g * 4 + oi;
            float acc = 0.f;
            #pragma unroll
            for (int c = 0; c < 13; ++c) acc = fmaf(W1[o * 13 + c], xr[c], acc);
            sg += acc; qg += acc * acc;
        }
        gsum[g] = sg; gsq[g] = qg;
    }
    block_reduce_write(gsum, gsq, p1 + ((size_t)b * NBLK_ + blockIdx.x) * 32);
}

// ---------------- stage2: conv1+GN1+relu+conv2 -> y2raw (bf16) + GN2 partial stats ----------------
__global__ __launch_bounds__(256) void stage2_kernel(const float* __restrict__ x0,
    const float* __restrict__ W1, const float* __restrict__ a1, const float* __restrict__ s1,
    const float* __restrict__ W2, bf16* __restrict__ y2raw, float* __restrict__ p2)
{
    __shared__ float aL[64], sL[64];
    int b = blockIdx.y;
    int col = blockIdx.x * 256 + threadIdx.x;
    if (threadIdx.x < 64) {
        aL[threadIdx.x] = a1[b * 64 + threadIdx.x];
        sL[threadIdx.x] = s1[b * 64 + threadIdx.x];
    }
    __syncthreads();
    const float* xb = x0 + (size_t)b * 13 * NK_ + col;
    float xr[13];
    #pragma unroll
    for (int c = 0; c < 13; ++c) xr[c] = xb[(size_t)c * NK_];
    float y1r[64];
    #pragma unroll
    for (int o = 0; o < 64; ++o) {
        float acc = 0.f;
        #pragma unroll
        for (int c = 0; c < 13; ++c) acc = fmaf(W1[o * 13 + c], xr[c], acc);
        y1r[o] = fmaxf(fmaf(acc, aL[o], sL[o]), 0.f);
    }
    bf16* yb = y2raw + (size_t)b * 64 * NK_ + col;
    float gsum[16], gsq[16];
    #pragma unroll
    for (int g = 0; g < 16; ++g) {
        float sg = 0.f, qg = 0.f;
        for (int oi = 0; oi < 4; ++oi) {
            int o = g * 4 + oi;
            float acc = 0.f;
            #pragma unroll
            for (int c = 0; c < 64; ++c) acc = fmaf(W2[o * 64 + c], y1r[c], acc);
            yb[(size_t)o * NK_] = f2b(acc);
            sg += acc; qg += acc * acc;   // stats on pre-rounding fp32
        }
        gsum[g] = sg; gsq[g] = qg;
    }
    block_reduce_write(gsum, gsq, p2 + ((size_t)b * NBLK_ + blockIdx.x) * 32);
}

// ---------------- stage3: GN2+relu on y2raw, conv3 -> y3 (bf16) + GN3 stats ----------------
__global__ __launch_bounds__(256) void stage3_kernel(const bf16* __restrict__ y2raw,
    const float* __restrict__ a2, const float* __restrict__ s2,
    const float* __restrict__ W3, bf16* __restrict__ y3, float* __restrict__ p3)
{
    __shared__ float a2L[64], s2L[64];
    int b = blockIdx.y;
    int col = blockIdx.x * 256 + threadIdx.x;
    if (threadIdx.x < 64) {
        a2L[threadIdx.x] = a2[b * 64 + threadIdx.x];
        s2L[threadIdx.x] = s2[b * 64 + threadIdx.x];
    }
    __syncthreads();
    const bf16* xb = y2raw + (size_t)b * 64 * NK_ + col;
    float y2r[64];
    #pragma unroll
    for (int c = 0; c < 64; ++c) {
        float v = b2f(xb[(size_t)c * NK_]);
        y2r[c] = fmaxf(fmaf(v, a2L[c], s2L[c]), 0.f);
    }
    bf16* yb = y3 + (size_t)b * 128 * NK_ + col;
    float gsum[16], gsq[16];
    #pragma unroll
    for (int g = 0; g < 16; ++g) {
        float sg = 0.f, qg = 0.f;
        for (int oi = 0; oi < 8; ++oi) {
            int o = g * 8 + oi;
            float acc = 0.f;
            #pragma unroll
            for (int c = 0; c < 64; ++c) acc = fmaf(W3[o * 64 + c], y2r[c], acc);
            yb[(size_t)o * NK_] = f2b(acc);
            sg += acc; qg += acc * acc;   // stats on pre-rounding fp32
        }
        gsum[g] = sg; gsq[g] = qg;
    }
    block_reduce_write(gsum, gsq, p3 + ((size_t)b * NBLK_ + blockIdx.x) * 32);
}

// ---------------- fold GN into per-(b,c) scale/shift from block partials ----------------
template<int COUT>
__global__ __launch_bounds__(256) void finalize_kernel(const float* __restrict__ part,
    const float* __restrict__ gamma, const float* __restrict__ beta,
    float* __restrict__ ga, float* __restrict__ sh)
{
    int t = blockIdx.x * 256 + threadIdx.x;
    if (t >= B_ * COUT) return;
    int b = t / COUT, c = t % COUT;
    int g = c / (COUT / G_);
    float sum = 0.f, sq = 0.f;
    for (int blk = 0; blk < NBLK_; ++blk) {
        sum += part[((size_t)b * NBLK_ + blk) * 32 + g];
        sq  += part[((size_t)b * NBLK_ + blk) * 32 + 16 + g];
    }
    float cnt = (float)(COUT / G_) * (float)NK_;
    float mean = sum / cnt;
    float var = fmaxf(sq / cnt - mean * mean, 0.f);
    float sc = gamma[c] * rsqrtf(var + EPS_);
    ga[t] = sc;
    sh[t] = beta[c] - mean * sc;
}

// ---------------- conv4 fused: OC4=16, one GN group per oy block ----------------
// grid (N/256, 16, B). part layout [b][g=oy][sum|sq][nx] -> 4*16*2*16 floats.
template<int OC4>
__global__ __launch_bounds__(256) void conv4_fused_kernel(
    const bf16* __restrict__ y3, const float* __restrict__ W4,
    const float* __restrict__ a3, const float* __restrict__ s3,
    float* __restrict__ m4, float* __restrict__ part)
{
    __shared__ float aL[128], sL[128];
    __shared__ float red[256];
    int nx = blockIdx.x, oy = blockIdx.y, b = blockIdx.z;
    int n = nx * 256 + threadIdx.x;
    int o0 = oy * OC4;
    for (int c = threadIdx.x; c < 128; c += 256) {
        aL[c] = a3[b * 128 + c];
        sL[c] = s3[b * 128 + c];
    }
    __syncthreads();
    const bf16* xb = y3 + (size_t)b * 128 * NK_ + n;
    float am[OC4];
    float ps = 0.f, pq = 0.f;
    #pragma unroll
    for (int o = 0; o < OC4; ++o) am[o] = -INFINITY;
    for (int k = 0; k < K_; ++k) {
        float acc[OC4];
        #pragma unroll
        for (int o = 0; o < OC4; ++o) acc[o] = 0.f;
        const bf16* xk = xb + (size_t)k * N_;
        #pragma unroll 8
        for (int c = 0; c < 128; ++c) {
            float v = fmaxf(fmaf(b2f(xk[(size_t)c * NK_]), aL[c], sL[c]), 0.f);
            #pragma unroll
            for (int o = 0; o < OC4; ++o)
                acc[o] = fmaf(W4[(o0 + o) * 128 + c], v, acc[o]);
        }
        #pragma unroll
        for (int o = 0; o < OC4; ++o) {
            float v = acc[o];
            am[o] = fmaxf(am[o], v);
            ps += v; pq += v * v;
        }
    }
    float* mb = m4 + ((size_t)b * 256 + o0) * N_ + n;
    #pragma unroll
    for (int o = 0; o < OC4; ++o) mb[(size_t)o * N_] = am[o];

    float vals[2] = { ps, pq };
    #pragma unroll
    for (int r = 0; r < 2; ++r) {
        red[threadIdx.x] = vals[r];
        __syncthreads();
        for (int h = 128; h > 0; h >>= 1) {
            if (threadIdx.x < h) red[threadIdx.x] += red[threadIdx.x + h];
            __syncthreads();
        }
        if (threadIdx.x == 0)
            part[((b * 16 + oy) * 2 + r) * 16 + nx] = red[0];
        __syncthreads();
    }
}

// ---------------- GN4 finalize from deterministic partials ----------------
__global__ __launch_bounds__(256) void finalize4_kernel(const float* __restrict__ part,
    const float* __restrict__ gamma, const float* __restrict__ beta,
    float* __restrict__ ga, float* __restrict__ sh)
{
    int t = blockIdx.x * 256 + threadIdx.x;   // B*256
    if (t >= B_ * 256) return;
    int b = t >> 8, c = t & 255;
    int g = c >> 4;                            // == oy block
    float sum = 0.f, sq = 0.f;
    for (int nx = 0; nx < 16; ++nx) {
        sum += part[((b * 16 + g) * 2 + 0) * 16 + nx];
        sq  += part[((b * 16 + g) * 2 + 1) * 16 + nx];
    }
    float cnt = 16.f * (float)NK_;
    float mean = sum / cnt;
    float var = fmaxf(sq / cnt - mean * mean, 0.f);
    float sc = gamma[c] * rsqrtf(var + EPS_);
    ga[t] = sc;
    sh[t] = beta[c] - mean * sc;
}

// ---------------- final: out = relu(a*max_k + s)  (valid since a>0) ----------------
__global__ __launch_bounds__(256) void apply_kernel(const float* __restrict__ m4,
    const float* __restrict__ ga, const float* __restrict__ sh, float* __restrict__ out)
{
    int t = blockIdx.x * 256 + threadIdx.x;   // b*256*N + c*N + n
    int bc = t >> 12;
    out[t] = fmaxf(fmaf(m4[t], ga[bc], sh[bc]), 0.f);
}

extern "C" void kernel_launch(void* const* d_in, const int* in_sizes, int n_in,
                              void* d_out, int out_size, void* d_ws, size_t ws_size,
                              hipStream_t stream)
{
    const float* pts = (const float*)d_in[0];
    const float* W1 = (const float*)d_in[1];
    const float* g1 = (const float*)d_in[2];
    const float* bt1 = (const float*)d_in[3];
    const float* W2 = (const float*)d_in[4];
    const float* g2 = (const float*)d_in[5];
    const float* bt2 = (const float*)d_in[6];
    const float* W3 = (const float*)d_in[7];
    const float* g3 = (const float*)d_in[8];
    const float* bt3 = (const float*)d_in[9];
    const float* W4 = (const float*)d_in[10];
    const float* g4 = (const float*)d_in[11];
    const float* bt4 = (const float*)d_in[12];
    float* out = (float*)d_out;

    char* ws = (char*)d_ws;
    size_t off = 0;
    auto alloc = [&](size_t bytes) -> void* {
        void* p = ws + off;
        off = (off + bytes + 255) & ~(size_t)255;
        return p;
    };
    int*   idx  = (int*)  alloc((size_t)B_ * NK_ * 4);           // 1.3 MB
    float* x0   = (float*)alloc((size_t)B_ * 13 * NK_ * 4);      // 17 MB
    bf16*  y2   = (bf16*) alloc((size_t)B_ * 64 * NK_ * 2);      // 42 MB
    bf16*  y3   = (bf16*) alloc((size_t)B_ * 128 * NK_ * 2);     // 84 MB
    float* m4   = (float*)alloc((size_t)B_ * 256 * N_ * 4);      // 16.8 MB
    float* p1   = (float*)alloc((size_t)B_ * NBLK_ * 32 * 4);    // 164 KB
    float* p2   = (float*)alloc((size_t)B_ * NBLK_ * 32 * 4);
    float* p3   = (float*)alloc((size_t)B_ * NBLK_ * 32 * 4);
    float* part4= (float*)alloc(2048 * 4);
    float* a1 = (float*)alloc(B_ * 64 * 4);
    float* s1 = (float*)alloc(B_ * 64 * 4);
    float* a2 = (float*)alloc(B_ * 64 * 4);
    float* s2 = (float*)alloc(B_ * 64 * 4);
    float* a3 = (float*)alloc(B_ * 128 * 4);
    float* s3 = (float*)alloc(B_ * 128 * 4);
    float* a4 = (float*)alloc(B_ * 256 * 4);
    float* s4 = (float*)alloc(B_ * 256 * 4);
    (void)ws_size; (void)in_sizes; (void)n_in; (void)out_size;

    knn_kernel<<<B_ * N_, 256, 0, stream>>>(pts, idx);
    feature_kernel<<<(B_ * NK_) / 256, 256, 0, stream>>>(pts, idx, x0);

    stage1_kernel<<<dim3(NBLK_, B_), 256, 0, stream>>>(x0, W1, p1);
    finalize_kernel<64><<<1, 256, 0, stream>>>(p1, g1, bt1, a1, s1);

    stage2_kernel<<<dim3(NBLK_, B_), 256, 0, stream>>>(x0, W1, a1, s1, W2, y2, p2);
    finalize_kernel<64><<<1, 256, 0, stream>>>(p2, g2, bt2, a2, s2);

    stage3_kernel<<<dim3(NBLK_, B_), 256, 0, stream>>>(y2, a2, s2, W3, y3, p3);
    finalize_kernel<128><<<2, 256, 0, stream>>>(p3, g3, bt3, a3, s3);

    conv4_fused_kernel<16><<<dim3(N_ / 256, 16, B_), 256, 0, stream>>>(y3, W4, a3, s3, m4, part4);
    finalize4_kernel<<<4, 256, 0, stream>>>(part4, g4, bt4, a4, s4);

    apply_kernel<<<(B_ * 256 * N_) / 256, 256, 0, stream>>>(m4, a4, s4, out);
}

// Round 12
// 1031.581 us; speedup vs baseline: 1.8354x; 1.3185x over previous
//
#include <hip/hip_runtime.h>
#include <hip/hip_bf16.h>
#include <math.h>

#define B_ 4
#define N_ 4096
#define K_ 20
#define NK_ (N_*K_)   // 81920
#define G_ 16
#define EPS_ 1e-5f
#define NBLK_ (NK_/256)   // 320 column-blocks per batch

typedef __hip_bfloat16 bf16;
__device__ inline float b2f(bf16 v) { return __bfloat162float(v); }
__device__ inline bf16  f2b(float v){ return __float2bfloat16(v); }

// ---------------- kNN: one WAVE per (b,i); candidates in registers; no barriers ----------------
// pd arithmetic bit-exact np (no FMA, sequential adds) — LOAD-BEARING, do not change.
// Tie-break: larger index wins (same as passing round 10; ties proven absent anyway).
__global__ __launch_bounds__(256) void knn_kernel(const float* __restrict__ pts, int* __restrict__ idx)
{
    int wid  = (blockIdx.x << 2) | (threadIdx.x >> 6);   // global wave id = b*N + i
    int lane = threadIdx.x & 63;
    int b = wid >> 12, i = wid & (N_ - 1);
    const float* pb = pts + (size_t)b * 6 * N_;
    float xi = pb[i], yi = pb[N_ + i], zi = pb[2 * N_ + i];
    float xxi = __fadd_rn(__fadd_rn(__fmul_rn(xi, xi), __fmul_rn(yi, yi)), __fmul_rn(zi, zi));
    float nxxi = -xxi;

    float pd[64];                    // candidate j = c*64 + lane  (statically indexed only)
    #pragma unroll
    for (int c = 0; c < 64; ++c) {
        int j = c * 64 + lane;
        float xj = pb[j], yj = pb[N_ + j], zj = pb[2 * N_ + j];
        float xxj = __fadd_rn(__fadd_rn(__fmul_rn(xj, xj), __fmul_rn(yj, yj)), __fmul_rn(zj, zj));
        float px = __fmul_rn(xi, xj);
        float py = __fmul_rn(yi, yj);
        float pz = __fmul_rn(zi, zj);
        float dot = __fadd_rn(__fadd_rn(px, py), pz);   // NO FMA — matches np
        float inner = __fmul_rn(-2.0f, dot);
        pd[c] = __fsub_rn(__fsub_rn(nxxi, inner), xxj);
    }

    unsigned mlo = 0xFFFFFFFFu, mhi = 0xFFFFFFFFu;      // live mask for slots 0-31 / 32-63
    for (int it = 0; it < K_; ++it) {
        float best = -INFINITY; int bc = 0;
        #pragma unroll
        for (int c = 0; c < 64; ++c) {
            unsigned ok = ((c < 32 ? (mlo >> c) : (mhi >> (c - 32))) & 1u);
            float v = ok ? pd[c] : -INFINITY;
            if (v >= best) { best = v; bc = c; }        // >=: larger c (larger j) wins lane ties
        }
        int bj = bc * 64 + lane;
        #pragma unroll
        for (int off = 1; off < 64; off <<= 1) {        // butterfly: all lanes converge
            float ov = __shfl_xor(best, off);
            int   oj = __shfl_xor(bj, off);
            if (ov > best || (ov == best && oj > bj)) { best = ov; bj = oj; }
        }
        if (lane == 0) idx[(size_t)b * NK_ + it * N_ + i] = bj;
        if ((bj & 63) == lane) {                        // owner retires the winning slot
            int cs = bj >> 6;
            unsigned bit = 1u << (cs & 31);
            if (cs < 32) mlo &= ~bit; else mhi &= ~bit;
        }
    }
}

// ---------------- angle: "x<0" quadrant predicate — LOAD-BEARING (round 10) ----------------
// Reference's atan2 lowering yields 0 (not IEEE pi) at (+0, -0). The degenerate
// self-neighbor slots (lxyz = +0 vector, d = -0 for all-negative normals) hit this.
__device__ inline float angle3(float ax, float ay, float az, float bx, float by, float bz)
{
    float cx = __fsub_rn(__fmul_rn(ay, bz), __fmul_rn(az, by));
    float cy = __fsub_rn(__fmul_rn(az, bx), __fmul_rn(ax, bz));
    float cz = __fsub_rn(__fmul_rn(ax, by), __fmul_rn(ay, bx));
    float cn = sqrtf(__fadd_rn(__fadd_rn(__fmul_rn(cx, cx), __fmul_rn(cy, cy)), __fmul_rn(cz, cz)));
    float d  = __fadd_rn(__fadd_rn(__fmul_rn(ax, bx), __fmul_rn(ay, by)), __fmul_rn(az, bz));
    if (cn == 0.0f)
        return (d < 0.0f) ? 3.14159274101257324e+00f : 0.0f;   // -0 -> 0
    return atan2f(cn, d);
}

__global__ __launch_bounds__(256) void feature_kernel(const float* __restrict__ pts,
                                                      const int* __restrict__ idx,
                                                      float* __restrict__ x0)
{
    int t = blockIdx.x * 256 + threadIdx.x;           // [0, B*NK)
    int col = t % NK_;
    int b = t / NK_;
    int n = col & (N_ - 1);
    int j = idx[t];
    const float* pb = pts + (size_t)b * 6 * N_;
    float cx = pb[n],            cy = pb[N_ + n],     cz = pb[2 * N_ + n];
    float gx = pb[j],            gy = pb[N_ + j],     gz = pb[2 * N_ + j];
    float rx = pb[3 * N_ + n],   ry = pb[4 * N_ + n], rz = pb[5 * N_ + n];
    float ix = pb[3 * N_ + j],   iy = pb[4 * N_ + j], iz = pb[5 * N_ + j];
    float lx = __fsub_rn(gx, cx), ly = __fsub_rn(gy, cy), lz = __fsub_rn(gz, cz);

    float f9  = angle3(rx, ry, rz, lx, ly, lz);
    float f10 = angle3(ix, iy, iz, lx, ly, lz);
    float f11 = angle3(rx, ry, rz, ix, iy, iz);
    float f12 = sqrtf(__fadd_rn(__fadd_rn(__fmul_rn(lx, lx), __fmul_rn(ly, ly)), __fmul_rn(lz, lz)));

    float* xp = x0 + (size_t)b * 13 * NK_ + col;
    xp[0  * (size_t)NK_] = gx;
    xp[1  * (size_t)NK_] = gy;
    xp[2  * (size_t)NK_] = gz;
    xp[3  * (size_t)NK_] = cx;
    xp[4  * (size_t)NK_] = cy;
    xp[5  * (size_t)NK_] = cz;
    xp[6  * (size_t)NK_] = lx;
    xp[7  * (size_t)NK_] = ly;
    xp[8  * (size_t)NK_] = lz;
    xp[9  * (size_t)NK_] = f9;
    xp[10 * (size_t)NK_] = f10;
    xp[11 * (size_t)NK_] = f11;
    xp[12 * (size_t)NK_] = f12;
}

// ---------------- deterministic block reduction: 16 sums + 16 sumsqs -> 32 partials ----------------
__device__ inline void block_reduce_write(const float gsum[16], const float gsq[16], float* __restrict__ dst)
{
    __shared__ float red[4][32];
    int t = threadIdx.x, lane = t & 63, w = t >> 6;
    #pragma unroll
    for (int r = 0; r < 16; ++r) {
        float v = gsum[r];
        #pragma unroll
        for (int off = 32; off > 0; off >>= 1) v += __shfl_down(v, off);
        if (lane == 0) red[w][r] = v;
        float q = gsq[r];
        #pragma unroll
        for (int off = 32; off > 0; off >>= 1) q += __shfl_down(q, off);
        if (lane == 0) red[w][16 + r] = q;
    }
    __syncthreads();
    if (t < 32) dst[t] = red[0][t] + red[1][t] + red[2][t] + red[3][t];
}

// ---------------- stage1: conv1 -> GN1 partial stats (y1 never stored) ----------------
__global__ __launch_bounds__(256) void stage1_kernel(const float* __restrict__ x0,
    const float* __restrict__ W1, float* __restrict__ p1)
{
    int b = blockIdx.y;
    int col = blockIdx.x * 256 + threadIdx.x;
    const float* xb = x0 + (size_t)b * 13 * NK_ + col;
    float xr[13];
    #pragma unroll
    for (int c = 0; c < 13; ++c) xr[c] = xb[(size_t)c * NK_];
    float gsum[16], gsq[16];
    #pragma unroll
    for (int g = 0; g < 16; ++g) {
        float sg = 0.f, qg = 0.f;
        for (int oi = 0; oi < 4; ++oi) {
            int o = g * 4 + oi;
            float acc = 0.f;
            #pragma unroll
            for (int c = 0; c < 13; ++c) acc = fmaf(W1[o * 13 + c], xr[c], acc);
            sg += acc; qg += acc * acc;
        }
        gsum[g] = sg; gsq[g] = qg;
    }
    block_reduce_write(gsum, gsq, p1 + ((size_t)b * NBLK_ + blockIdx.x) * 32);
}

// ---------------- stage2: conv1+GN1+relu+conv2 -> y2raw (bf16) + GN2 partial stats ----------------
__global__ __launch_bounds__(256) void stage2_kernel(const float* __restrict__ x0,
    const float* __restrict__ W1, const float* __restrict__ a1, const float* __restrict__ s1,
    const float* __restrict__ W2, bf16* __restrict__ y2raw, float* __restrict__ p2)
{
    __shared__ float aL[64], sL[64];
    int b = blockIdx.y;
    int col = blockIdx.x * 256 + threadIdx.x;
    if (threadIdx.x < 64) {
        aL[threadIdx.x] = a1[b * 64 + threadIdx.x];
        sL[threadIdx.x] = s1[b * 64 + threadIdx.x];
    }
    __syncthreads();
    const float* xb = x0 + (size_t)b * 13 * NK_ + col;
    float xr[13];
    #pragma unroll
    for (int c = 0; c < 13; ++c) xr[c] = xb[(size_t)c * NK_];
    float y1r[64];
    #pragma unroll
    for (int o = 0; o < 64; ++o) {
        float acc = 0.f;
        #pragma unroll
        for (int c = 0; c < 13; ++c) acc = fmaf(W1[o * 13 + c], xr[c], acc);
        y1r[o] = fmaxf(fmaf(acc, aL[o], sL[o]), 0.f);
    }
    bf16* yb = y2raw + (size_t)b * 64 * NK_ + col;
    float gsum[16], gsq[16];
    #pragma unroll
    for (int g = 0; g < 16; ++g) {
        float sg = 0.f, qg = 0.f;
        for (int oi = 0; oi < 4; ++oi) {
            int o = g * 4 + oi;
            float acc = 0.f;
            #pragma unroll
            for (int c = 0; c < 64; ++c) acc = fmaf(W2[o * 64 + c], y1r[c], acc);
            yb[(size_t)o * NK_] = f2b(acc);
            sg += acc; qg += acc * acc;   // stats on pre-rounding fp32
        }
        gsum[g] = sg; gsq[g] = qg;
    }
    block_reduce_write(gsum, gsq, p2 + ((size_t)b * NBLK_ + blockIdx.x) * 32);
}

// ---------------- stage3: GN2+relu on y2raw, conv3 -> y3 (bf16) + GN3 stats ----------------
__global__ __launch_bounds__(256) void stage3_kernel(const bf16* __restrict__ y2raw,
    const float* __restrict__ a2, const float* __restrict__ s2,
    const float* __restrict__ W3, bf16* __restrict__ y3, float* __restrict__ p3)
{
    __shared__ float a2L[64], s2L[64];
    int b = blockIdx.y;
    int col = blockIdx.x * 256 + threadIdx.x;
    if (threadIdx.x < 64) {
        a2L[threadIdx.x] = a2[b * 64 + threadIdx.x];
        s2L[threadIdx.x] = s2[b * 64 + threadIdx.x];
    }
    __syncthreads();
    const bf16* xb = y2raw + (size_t)b * 64 * NK_ + col;
    float y2r[64];
    #pragma unroll
    for (int c = 0; c < 64; ++c) {
        float v = b2f(xb[(size_t)c * NK_]);
        y2r[c] = fmaxf(fmaf(v, a2L[c], s2L[c]), 0.f);
    }
    bf16* yb = y3 + (size_t)b * 128 * NK_ + col;
    float gsum[16], gsq[16];
    #pragma unroll
    for (int g = 0; g < 16; ++g) {
        float sg = 0.f, qg = 0.f;
        for (int oi = 0; oi < 8; ++oi) {
            int o = g * 8 + oi;
            float acc = 0.f;
            #pragma unroll
            for (int c = 0; c < 64; ++c) acc = fmaf(W3[o * 64 + c], y2r[c], acc);
            yb[(size_t)o * NK_] = f2b(acc);
            sg += acc; qg += acc * acc;   // stats on pre-rounding fp32
        }
        gsum[g] = sg; gsq[g] = qg;
    }
    block_reduce_write(gsum, gsq, p3 + ((size_t)b * NBLK_ + blockIdx.x) * 32);
}

// ---------------- fold GN into per-(b,c) scale/shift from block partials ----------------
template<int COUT>
__global__ __launch_bounds__(256) void finalize_kernel(const float* __restrict__ part,
    const float* __restrict__ gamma, const float* __restrict__ beta,
    float* __restrict__ ga, float* __restrict__ sh)
{
    int t = blockIdx.x * 256 + threadIdx.x;
    if (t >= B_ * COUT) return;
    int b = t / COUT, c = t % COUT;
    int g = c / (COUT / G_);
    float sum = 0.f, sq = 0.f;
    for (int blk = 0; blk < NBLK_; ++blk) {
        sum += part[((size_t)b * NBLK_ + blk) * 32 + g];
        sq  += part[((size_t)b * NBLK_ + blk) * 32 + 16 + g];
    }
    float cnt = (float)(COUT / G_) * (float)NK_;
    float mean = sum / cnt;
    float var = fmaxf(sq / cnt - mean * mean, 0.f);
    float sc = gamma[c] * rsqrtf(var + EPS_);
    ga[t] = sc;
    sh[t] = beta[c] - mean * sc;
}

// ---------------- conv4 fused: OC4=16, one GN group per oy block ----------------
template<int OC4>
__global__ __launch_bounds__(256) void conv4_fused_kernel(
    const bf16* __restrict__ y3, const float* __restrict__ W4,
    const float* __restrict__ a3, const float* __restrict__ s3,
    float* __restrict__ m4, float* __restrict__ part)
{
    __shared__ float aL[128], sL[128];
    __shared__ float red[256];
    int nx = blockIdx.x, oy = blockIdx.y, b = blockIdx.z;
    int n = nx * 256 + threadIdx.x;
    int o0 = oy * OC4;
    for (int c = threadIdx.x; c < 128; c += 256) {
        aL[c] = a3[b * 128 + c];
        sL[c] = s3[b * 128 + c];
    }
    __syncthreads();
    const bf16* xb = y3 + (size_t)b * 128 * NK_ + n;
    float am[OC4];
    float ps = 0.f, pq = 0.f;
    #pragma unroll
    for (int o = 0; o < OC4; ++o) am[o] = -INFINITY;
    for (int k = 0; k < K_; ++k) {
        float acc[OC4];
        #pragma unroll
        for (int o = 0; o < OC4; ++o) acc[o] = 0.f;
        const bf16* xk = xb + (size_t)k * N_;
        #pragma unroll 8
        for (int c = 0; c < 128; ++c) {
            float v = fmaxf(fmaf(b2f(xk[(size_t)c * NK_]), aL[c], sL[c]), 0.f);
            #pragma unroll
            for (int o = 0; o < OC4; ++o)
                acc[o] = fmaf(W4[(o0 + o) * 128 + c], v, acc[o]);
        }
        #pragma unroll
        for (int o = 0; o < OC4; ++o) {
            float v = acc[o];
            am[o] = fmaxf(am[o], v);
            ps += v; pq += v * v;
        }
    }
    float* mb = m4 + ((size_t)b * 256 + o0) * N_ + n;
    #pragma unroll
    for (int o = 0; o < OC4; ++o) mb[(size_t)o * N_] = am[o];

    float vals[2] = { ps, pq };
    #pragma unroll
    for (int r = 0; r < 2; ++r) {
        red[threadIdx.x] = vals[r];
        __syncthreads();
        for (int h = 128; h > 0; h >>= 1) {
            if (threadIdx.x < h) red[threadIdx.x] += red[threadIdx.x + h];
            __syncthreads();
        }
        if (threadIdx.x == 0)
            part[((b * 16 + oy) * 2 + r) * 16 + nx] = red[0];
        __syncthreads();
    }
}

// ---------------- GN4 finalize from deterministic partials ----------------
__global__ __launch_bounds__(256) void finalize4_kernel(const float* __restrict__ part,
    const float* __restrict__ gamma, const float* __restrict__ beta,
    float* __restrict__ ga, float* __restrict__ sh)
{
    int t = blockIdx.x * 256 + threadIdx.x;   // B*256
    if (t >= B_ * 256) return;
    int b = t >> 8, c = t & 255;
    int g = c >> 4;                            // == oy block
    float sum = 0.f, sq = 0.f;
    for (int nx = 0; nx < 16; ++nx) {
        sum += part[((b * 16 + g) * 2 + 0) * 16 + nx];
        sq  += part[((b * 16 + g) * 2 + 1) * 16 + nx];
    }
    float cnt = 16.f * (float)NK_;
    float mean = sum / cnt;
    float var = fmaxf(sq / cnt - mean * mean, 0.f);
    float sc = gamma[c] * rsqrtf(var + EPS_);
    ga[t] = sc;
    sh[t] = beta[c] - mean * sc;
}

// ---------------- final: out = relu(a*max_k + s)  (valid since a>0) ----------------
__global__ __launch_bounds__(256) void apply_kernel(const float* __restrict__ m4,
    const float* __restrict__ ga, const float* __restrict__ sh, float* __restrict__ out)
{
    int t = blockIdx.x * 256 + threadIdx.x;   // b*256*N + c*N + n
    int bc = t >> 12;
    out[t] = fmaxf(fmaf(m4[t], ga[bc], sh[bc]), 0.f);
}

extern "C" void kernel_launch(void* const* d_in, const int* in_sizes, int n_in,
                              void* d_out, int out_size, void* d_ws, size_t ws_size,
                              hipStream_t stream)
{
    const float* pts = (const float*)d_in[0];
    const float* W1 = (const float*)d_in[1];
    const float* g1 = (const float*)d_in[2];
    const float* bt1 = (const float*)d_in[3];
    const float* W2 = (const float*)d_in[4];
    const float* g2 = (const float*)d_in[5];
    const float* bt2 = (const float*)d_in[6];
    const float* W3 = (const float*)d_in[7];
    const float* g3 = (const float*)d_in[8];
    const float* bt3 = (const float*)d_in[9];
    const float* W4 = (const float*)d_in[10];
    const float* g4 = (const float*)d_in[11];
    const float* bt4 = (const float*)d_in[12];
    float* out = (float*)d_out;

    char* ws = (char*)d_ws;
    size_t off = 0;
    auto alloc = [&](size_t bytes) -> void* {
        void* p = ws + off;
        off = (off + bytes + 255) & ~(size_t)255;
        return p;
    };
    int*   idx  = (int*)  alloc((size_t)B_ * NK_ * 4);           // 1.3 MB
    float* x0   = (float*)alloc((size_t)B_ * 13 * NK_ * 4);      // 17 MB
    bf16*  y2   = (bf16*) alloc((size_t)B_ * 64 * NK_ * 2);      // 42 MB
    bf16*  y3   = (bf16*) alloc((size_t)B_ * 128 * NK_ * 2);     // 84 MB
    float* m4   = (float*)alloc((size_t)B_ * 256 * N_ * 4);      // 16.8 MB
    float* p1   = (float*)alloc((size_t)B_ * NBLK_ * 32 * 4);    // 164 KB
    float* p2   = (float*)alloc((size_t)B_ * NBLK_ * 32 * 4);
    float* p3   = (float*)alloc((size_t)B_ * NBLK_ * 32 * 4);
    float* part4= (float*)alloc(2048 * 4);
    float* a1 = (float*)alloc(B_ * 64 * 4);
    float* s1 = (float*)alloc(B_ * 64 * 4);
    float* a2 = (float*)alloc(B_ * 64 * 4);
    float* s2 = (float*)alloc(B_ * 64 * 4);
    float* a3 = (float*)alloc(B_ * 128 * 4);
    float* s3 = (float*)alloc(B_ * 128 * 4);
    float* a4 = (float*)alloc(B_ * 256 * 4);
    float* s4 = (float*)alloc(B_ * 256 * 4);
    (void)ws_size; (void)in_sizes; (void)n_in; (void)out_size;

    knn_kernel<<<(B_ * N_) / 4, 256, 0, stream>>>(pts, idx);
    feature_kernel<<<(B_ * NK_) / 256, 256, 0, stream>>>(pts, idx, x0);

    stage1_kernel<<<dim3(NBLK_, B_), 256, 0, stream>>>(x0, W1, p1);
    finalize_kernel<64><<<1, 256, 0, stream>>>(p1, g1, bt1, a1, s1);

    stage2_kernel<<<dim3(NBLK_, B_), 256, 0, stream>>>(x0, W1, a1, s1, W2, y2, p2);
    finalize_kernel<64><<<1, 256, 0, stream>>>(p2, g2, bt2, a2, s2);

    stage3_kernel<<<dim3(NBLK_, B_), 256, 0, stream>>>(y2, a2, s2, W3, y3, p3);
    finalize_kernel<128><<<2, 256, 0, stream>>>(p3, g3, bt3, a3, s3);

    conv4_fused_kernel<16><<<dim3(N_ / 256, 16, B_), 256, 0, stream>>>(y3, W4, a3, s3, m4, part4);
    finalize4_kernel<<<4, 256, 0, stream>>>(part4, g4, bt4, a4, s4);

    apply_kernel<<<(B_ * 256 * N_) / 256, 256, 0, stream>>>(m4, a4, s4, out);
}

// Round 13
// 794.430 us; speedup vs baseline: 2.3833x; 1.2985x over previous
//
#include <hip/hip_runtime.h>
#include <hip/hip_bf16.h>
#include <math.h>

#define B_ 4
#define N_ 4096
#define K_ 20
#define NK_ (N_*K_)   // 81920
#define G_ 16
#define EPS_ 1e-5f
#define NBLK_ (NK_/256)   // 320 column-blocks per batch

typedef __hip_bfloat16 bf16;
typedef short bf16x8v __attribute__((ext_vector_type(8)));
typedef unsigned short u16x8v __attribute__((ext_vector_type(8)));
typedef float f32x4v __attribute__((ext_vector_type(4)));

__device__ inline float b2f(bf16 v) { return __bfloat162float(v); }
__device__ inline bf16  f2b(float v){ return __float2bfloat16(v); }
__device__ inline float us2f(unsigned short u){ unsigned int i = ((unsigned)u) << 16; float f; __builtin_memcpy(&f, &i, 4); return f; }
__device__ inline unsigned short f2us(float f){ bf16 h = __float2bfloat16(f); unsigned short u; __builtin_memcpy(&u, &h, 2); return u; }

// ---------------- kNN: one WAVE per (b,i); candidates in registers; no barriers ----------------
// pd arithmetic bit-exact np (no FMA, sequential adds) — LOAD-BEARING, do not change.
__global__ __launch_bounds__(256) void knn_kernel(const float* __restrict__ pts, int* __restrict__ idx)
{
    int wid  = (blockIdx.x << 2) | (threadIdx.x >> 6);   // global wave id = b*N + i
    int lane = threadIdx.x & 63;
    int b = wid >> 12, i = wid & (N_ - 1);
    const float* pb = pts + (size_t)b * 6 * N_;
    float xi = pb[i], yi = pb[N_ + i], zi = pb[2 * N_ + i];
    float xxi = __fadd_rn(__fadd_rn(__fmul_rn(xi, xi), __fmul_rn(yi, yi)), __fmul_rn(zi, zi));
    float nxxi = -xxi;

    float pd[64];                    // candidate j = c*64 + lane  (statically indexed only)
    #pragma unroll
    for (int c = 0; c < 64; ++c) {
        int j = c * 64 + lane;
        float xj = pb[j], yj = pb[N_ + j], zj = pb[2 * N_ + j];
        float xxj = __fadd_rn(__fadd_rn(__fmul_rn(xj, xj), __fmul_rn(yj, yj)), __fmul_rn(zj, zj));
        float px = __fmul_rn(xi, xj);
        float py = __fmul_rn(yi, yj);
        float pz = __fmul_rn(zi, zj);
        float dot = __fadd_rn(__fadd_rn(px, py), pz);   // NO FMA — matches np
        float inner = __fmul_rn(-2.0f, dot);
        pd[c] = __fsub_rn(__fsub_rn(nxxi, inner), xxj);
    }

    unsigned mlo = 0xFFFFFFFFu, mhi = 0xFFFFFFFFu;      // live mask for slots 0-31 / 32-63
    for (int it = 0; it < K_; ++it) {
        float best = -INFINITY; int bc = 0;
        #pragma unroll
        for (int c = 0; c < 64; ++c) {
            unsigned ok = ((c < 32 ? (mlo >> c) : (mhi >> (c - 32))) & 1u);
            float v = ok ? pd[c] : -INFINITY;
            if (v >= best) { best = v; bc = c; }        // >=: larger c (larger j) wins lane ties
        }
        int bj = bc * 64 + lane;
        #pragma unroll
        for (int off = 1; off < 64; off <<= 1) {        // butterfly: all lanes converge
            float ov = __shfl_xor(best, off);
            int   oj = __shfl_xor(bj, off);
            if (ov > best || (ov == best && oj > bj)) { best = ov; bj = oj; }
        }
        if (lane == 0) idx[(size_t)b * NK_ + it * N_ + i] = bj;
        if ((bj & 63) == lane) {                        // owner retires the winning slot
            int cs = bj >> 6;
            unsigned bit = 1u << (cs & 31);
            if (cs < 32) mlo &= ~bit; else mhi &= ~bit;
        }
    }
}

// ---------------- angle: "x<0" quadrant predicate — LOAD-BEARING (round 10) ----------------
__device__ inline float angle3(float ax, float ay, float az, float bx, float by, float bz)
{
    float cx = __fsub_rn(__fmul_rn(ay, bz), __fmul_rn(az, by));
    float cy = __fsub_rn(__fmul_rn(az, bx), __fmul_rn(ax, bz));
    float cz = __fsub_rn(__fmul_rn(ax, by), __fmul_rn(ay, bx));
    float cn = sqrtf(__fadd_rn(__fadd_rn(__fmul_rn(cx, cx), __fmul_rn(cy, cy)), __fmul_rn(cz, cz)));
    float d  = __fadd_rn(__fadd_rn(__fmul_rn(ax, bx), __fmul_rn(ay, by)), __fmul_rn(az, bz));
    if (cn == 0.0f)
        return (d < 0.0f) ? 3.14159274101257324e+00f : 0.0f;   // -0 -> 0
    return atan2f(cn, d);
}

__global__ __launch_bounds__(256) void feature_kernel(const float* __restrict__ pts,
                                                      const int* __restrict__ idx,
                                                      float* __restrict__ x0)
{
    int t = blockIdx.x * 256 + threadIdx.x;           // [0, B*NK)
    int col = t % NK_;
    int b = t / NK_;
    int n = col & (N_ - 1);
    int j = idx[t];
    const float* pb = pts + (size_t)b * 6 * N_;
    float cx = pb[n],            cy = pb[N_ + n],     cz = pb[2 * N_ + n];
    float gx = pb[j],            gy = pb[N_ + j],     gz = pb[2 * N_ + j];
    float rx = pb[3 * N_ + n],   ry = pb[4 * N_ + n], rz = pb[5 * N_ + n];
    float ix = pb[3 * N_ + j],   iy = pb[4 * N_ + j], iz = pb[5 * N_ + j];
    float lx = __fsub_rn(gx, cx), ly = __fsub_rn(gy, cy), lz = __fsub_rn(gz, cz);

    float f9  = angle3(rx, ry, rz, lx, ly, lz);
    float f10 = angle3(ix, iy, iz, lx, ly, lz);
    float f11 = angle3(rx, ry, rz, ix, iy, iz);
    float f12 = sqrtf(__fadd_rn(__fadd_rn(__fmul_rn(lx, lx), __fmul_rn(ly, ly)), __fmul_rn(lz, lz)));

    float* xp = x0 + (size_t)b * 13 * NK_ + col;
    xp[0  * (size_t)NK_] = gx;
    xp[1  * (size_t)NK_] = gy;
    xp[2  * (size_t)NK_] = gz;
    xp[3  * (size_t)NK_] = cx;
    xp[4  * (size_t)NK_] = cy;
    xp[5  * (size_t)NK_] = cz;
    xp[6  * (size_t)NK_] = lx;
    xp[7  * (size_t)NK_] = ly;
    xp[8  * (size_t)NK_] = lz;
    xp[9  * (size_t)NK_] = f9;
    xp[10 * (size_t)NK_] = f10;
    xp[11 * (size_t)NK_] = f11;
    xp[12 * (size_t)NK_] = f12;
}

// ---------------- deterministic block reduction: 16 sums + 16 sumsqs -> 32 partials ----------------
__device__ inline void block_reduce_write(const float gsum[16], const float gsq[16], float* __restrict__ dst)
{
    __shared__ float red[4][32];
    int t = threadIdx.x, lane = t & 63, w = t >> 6;
    #pragma unroll
    for (int r = 0; r < 16; ++r) {
        float v = gsum[r];
        #pragma unroll
        for (int off = 32; off > 0; off >>= 1) v += __shfl_down(v, off);
        if (lane == 0) red[w][r] = v;
        float q = gsq[r];
        #pragma unroll
        for (int off = 32; off > 0; off >>= 1) q += __shfl_down(q, off);
        if (lane == 0) red[w][16 + r] = q;
    }
    __syncthreads();
    if (t < 32) dst[t] = red[0][t] + red[1][t] + red[2][t] + red[3][t];
}

// ---------------- stage1: conv1 -> GN1 partial stats (y1 never stored) ----------------
__global__ __launch_bounds__(256) void stage1_kernel(const float* __restrict__ x0,
    const float* __restrict__ W1, float* __restrict__ p1)
{
    int b = blockIdx.y;
    int col = blockIdx.x * 256 + threadIdx.x;
    const float* xb = x0 + (size_t)b * 13 * NK_ + col;
    float xr[13];
    #pragma unroll
    for (int c = 0; c < 13; ++c) xr[c] = xb[(size_t)c * NK_];
    float gsum[16], gsq[16];
    #pragma unroll
    for (int g = 0; g < 16; ++g) {
        float sg = 0.f, qg = 0.f;
        for (int oi = 0; oi < 4; ++oi) {
            int o = g * 4 + oi;
            float acc = 0.f;
            #pragma unroll
            for (int c = 0; c < 13; ++c) acc = fmaf(W1[o * 13 + c], xr[c], acc);
            sg += acc; qg += acc * acc;
        }
        gsum[g] = sg; gsq[g] = qg;
    }
    block_reduce_write(gsum, gsq, p1 + ((size_t)b * NBLK_ + blockIdx.x) * 32);
}

// ---------------- stage2: conv1+GN1+relu+conv2 -> y2raw (bf16) + GN2 partial stats ----------------
__global__ __launch_bounds__(256) void stage2_kernel(const float* __restrict__ x0,
    const float* __restrict__ W1, const float* __restrict__ a1, const float* __restrict__ s1,
    const float* __restrict__ W2, bf16* __restrict__ y2raw, float* __restrict__ p2)
{
    __shared__ float aL[64], sL[64];
    int b = blockIdx.y;
    int col = blockIdx.x * 256 + threadIdx.x;
    if (threadIdx.x < 64) {
        aL[threadIdx.x] = a1[b * 64 + threadIdx.x];
        sL[threadIdx.x] = s1[b * 64 + threadIdx.x];
    }
    __syncthreads();
    const float* xb = x0 + (size_t)b * 13 * NK_ + col;
    float xr[13];
    #pragma unroll
    for (int c = 0; c < 13; ++c) xr[c] = xb[(size_t)c * NK_];
    float y1r[64];
    #pragma unroll
    for (int o = 0; o < 64; ++o) {
        float acc = 0.f;
        #pragma unroll
        for (int c = 0; c < 13; ++c) acc = fmaf(W1[o * 13 + c], xr[c], acc);
        y1r[o] = fmaxf(fmaf(acc, aL[o], sL[o]), 0.f);
    }
    bf16* yb = y2raw + (size_t)b * 64 * NK_ + col;
    float gsum[16], gsq[16];
    #pragma unroll
    for (int g = 0; g < 16; ++g) {
        float sg = 0.f, qg = 0.f;
        for (int oi = 0; oi < 4; ++oi) {
            int o = g * 4 + oi;
            float acc = 0.f;
            #pragma unroll
            for (int c = 0; c < 64; ++c) acc = fmaf(W2[o * 64 + c], y1r[c], acc);
            yb[(size_t)o * NK_] = f2b(acc);
            sg += acc; qg += acc * acc;   // stats on pre-rounding fp32
        }
        gsum[g] = sg; gsq[g] = qg;
    }
    block_reduce_write(gsum, gsq, p2 + ((size_t)b * NBLK_ + blockIdx.x) * 32);
}

// ---------------- stage3: GN2+relu on y2raw, conv3 -> y3 (bf16) + GN3 stats ----------------
__global__ __launch_bounds__(256) void stage3_kernel(const bf16* __restrict__ y2raw,
    const float* __restrict__ a2, const float* __restrict__ s2,
    const float* __restrict__ W3, bf16* __restrict__ y3, float* __restrict__ p3)
{
    __shared__ float a2L[64], s2L[64];
    int b = blockIdx.y;
    int col = blockIdx.x * 256 + threadIdx.x;
    if (threadIdx.x < 64) {
        a2L[threadIdx.x] = a2[b * 64 + threadIdx.x];
        s2L[threadIdx.x] = s2[b * 64 + threadIdx.x];
    }
    __syncthreads();
    const bf16* xb = y2raw + (size_t)b * 64 * NK_ + col;
    float y2r[64];
    #pragma unroll
    for (int c = 0; c < 64; ++c) {
        float v = b2f(xb[(size_t)c * NK_]);
        y2r[c] = fmaxf(fmaf(v, a2L[c], s2L[c]), 0.f);
    }
    bf16* yb = y3 + (size_t)b * 128 * NK_ + col;
    float gsum[16], gsq[16];
    #pragma unroll
    for (int g = 0; g < 16; ++g) {
        float sg = 0.f, qg = 0.f;
        for (int oi = 0; oi < 8; ++oi) {
            int o = g * 8 + oi;
            float acc = 0.f;
            #pragma unroll
            for (int c = 0; c < 64; ++c) acc = fmaf(W3[o * 64 + c], y2r[c], acc);
            yb[(size_t)o * NK_] = f2b(acc);
            sg += acc; qg += acc * acc;   // stats on pre-rounding fp32
        }
        gsum[g] = sg; gsq[g] = qg;
    }
    block_reduce_write(gsum, gsq, p3 + ((size_t)b * NBLK_ + blockIdx.x) * 32);
}

// ---------------- fold GN into per-(b,c) scale/shift from block partials ----------------
template<int COUT>
__global__ __launch_bounds__(256) void finalize_kernel(const float* __restrict__ part,
    const float* __restrict__ gamma, const float* __restrict__ beta,
    float* __restrict__ ga, float* __restrict__ sh)
{
    int t = blockIdx.x * 256 + threadIdx.x;
    if (t >= B_ * COUT) return;
    int b = t / COUT, c = t % COUT;
    int g = c / (COUT / G_);
    float sum = 0.f, sq = 0.f;
    for (int blk = 0; blk < NBLK_; ++blk) {
        sum += part[((size_t)b * NBLK_ + blk) * 32 + g];
        sq  += part[((size_t)b * NBLK_ + blk) * 32 + 16 + g];
    }
    float cnt = (float)(COUT / G_) * (float)NK_;
    float mean = sum / cnt;
    float var = fmaxf(sq / cnt - mean * mean, 0.f);
    float sc = gamma[c] * rsqrtf(var + EPS_);
    ga[t] = sc;
    sh[t] = beta[c] - mean * sc;
}

// ---------------- W4 -> bf16 ----------------
__global__ __launch_bounds__(256) void w4b_kernel(const float* __restrict__ W4, bf16* __restrict__ w4b)
{
    int t = blockIdx.x * 256 + threadIdx.x;   // 256*128 = 32768
    if (t < 256 * 128) w4b[t] = f2b(W4[t]);
}

// ---------------- prep4: in-place x3 = bf16(relu(a3*y3 + s3)) on y3 buffer ----------------
__global__ __launch_bounds__(256) void prep4_kernel(unsigned short* __restrict__ y3,
    const float* __restrict__ a3, const float* __restrict__ s3)
{
    size_t t = (size_t)blockIdx.x * 256 + threadIdx.x;   // one thread = 8 elems, same (b,c)
    size_t e8 = t * 8;
    int b = (int)(e8 / ((size_t)128 * NK_));
    int c = (int)((e8 / NK_) & 127);
    float a = a3[b * 128 + c], s = s3[b * 128 + c];
    u16x8v v = *reinterpret_cast<const u16x8v*>(y3 + e8);
    #pragma unroll
    for (int j = 0; j < 8; ++j)
        v[j] = f2us(fmaxf(fmaf(us2f(v[j]), a, s), 0.f));
    *reinterpret_cast<u16x8v*>(y3 + e8) = v;
}

// ---------------- conv4 via MFMA: wave = 16o x 16n tile, max over k, GN4 group stats ----------------
// A = W4b (16x32 frag: o=lane&15, k-group=lane>>4), B = x3 (32x16: col=lane&15),
// D map col=lane&15, row=(lane>>4)*4+j (m89-verified). part: [b][g=16][2][ntile=256].
__global__ __launch_bounds__(256) void conv4_mfma_kernel(
    const short* __restrict__ x3, const short* __restrict__ w4b,
    float* __restrict__ m4, float* __restrict__ part)
{
    int ntile = blockIdx.x, oy = blockIdx.y, b = blockIdx.z;
    int lane = threadIdx.x & 63, w = threadIdx.x >> 6;
    int n0 = ntile * 16;
    int obase = oy * 64 + w * 16;

    bf16x8v afr[4];
    #pragma unroll
    for (int cb = 0; cb < 4; ++cb) {
        size_t aoff = (size_t)(obase + (lane & 15)) * 128 + cb * 32 + (lane >> 4) * 8;
        afr[cb] = *reinterpret_cast<const bf16x8v*>(w4b + aoff);
    }

    const short* xb = x3 + (size_t)b * 128 * NK_;
    int colme = n0 + (lane & 15);
    int cme = (lane >> 4) * 8;

    float am[4] = { -INFINITY, -INFINITY, -INFINITY, -INFINITY };
    float ps = 0.f, pq = 0.f;
    for (int k = 0; k < K_; ++k) {
        const short* xc = xb + (size_t)(k * N_ + colme);
        f32x4v acc = { 0.f, 0.f, 0.f, 0.f };
        #pragma unroll
        for (int cb = 0; cb < 4; ++cb) {
            bf16x8v bfr;
            #pragma unroll
            for (int i = 0; i < 8; ++i)
                bfr[i] = xc[(size_t)(cb * 32 + cme + i) * NK_];
            acc = __builtin_amdgcn_mfma_f32_16x16x32_bf16(afr[cb], bfr, acc, 0, 0, 0);
        }
        #pragma unroll
        for (int j = 0; j < 4; ++j) {
            float v = acc[j];
            am[j] = fmaxf(am[j], v);
            ps += v; pq += v * v;
        }
    }
    #pragma unroll
    for (int j = 0; j < 4; ++j) {
        int o = obase + (lane >> 4) * 4 + j;
        m4[((size_t)b * 256 + o) * N_ + colme] = am[j];
    }
    #pragma unroll
    for (int off = 32; off > 0; off >>= 1) {
        ps += __shfl_down(ps, off);
        pq += __shfl_down(pq, off);
    }
    if (lane == 0) {
        int g = oy * 4 + w;                      // wave's 16 o == one GN4 group
        part[((b * 16 + g) * 2 + 0) * 256 + ntile] = ps;
        part[((b * 16 + g) * 2 + 1) * 256 + ntile] = pq;
    }
}

// ---------------- GN4 finalize from deterministic partials ----------------
__global__ __launch_bounds__(256) void finalize4_kernel(const float* __restrict__ part,
    const float* __restrict__ gamma, const float* __restrict__ beta,
    float* __restrict__ ga, float* __restrict__ sh)
{
    int t = blockIdx.x * 256 + threadIdx.x;   // B*256
    if (t >= B_ * 256) return;
    int b = t >> 8, c = t & 255;
    int g = c >> 4;
    float sum = 0.f, sq = 0.f;
    for (int nt = 0; nt < 256; ++nt) {
        sum += part[((b * 16 + g) * 2 + 0) * 256 + nt];
        sq  += part[((b * 16 + g) * 2 + 1) * 256 + nt];
    }
    float cnt = 16.f * (float)NK_;
    float mean = sum / cnt;
    float var = fmaxf(sq / cnt - mean * mean, 0.f);
    float sc = gamma[c] * rsqrtf(var + EPS_);
    ga[t] = sc;
    sh[t] = beta[c] - mean * sc;
}

// ---------------- final: out = relu(a*max_k + s)  (valid since a>0) ----------------
__global__ __launch_bounds__(256) void apply_kernel(const float* __restrict__ m4,
    const float* __restrict__ ga, const float* __restrict__ sh, float* __restrict__ out)
{
    int t = blockIdx.x * 256 + threadIdx.x;   // b*256*N + c*N + n
    int bc = t >> 12;
    out[t] = fmaxf(fmaf(m4[t], ga[bc], sh[bc]), 0.f);
}

extern "C" void kernel_launch(void* const* d_in, const int* in_sizes, int n_in,
                              void* d_out, int out_size, void* d_ws, size_t ws_size,
                              hipStream_t stream)
{
    const float* pts = (const float*)d_in[0];
    const float* W1 = (const float*)d_in[1];
    const float* g1 = (const float*)d_in[2];
    const float* bt1 = (const float*)d_in[3];
    const float* W2 = (const float*)d_in[4];
    const float* g2 = (const float*)d_in[5];
    const float* bt2 = (const float*)d_in[6];
    const float* W3 = (const float*)d_in[7];
    const float* g3 = (const float*)d_in[8];
    const float* bt3 = (const float*)d_in[9];
    const float* W4 = (const float*)d_in[10];
    const float* g4 = (const float*)d_in[11];
    const float* bt4 = (const float*)d_in[12];
    float* out = (float*)d_out;

    char* ws = (char*)d_ws;
    size_t off = 0;
    auto alloc = [&](size_t bytes) -> void* {
        void* p = ws + off;
        off = (off + bytes + 255) & ~(size_t)255;
        return p;
    };
    int*   idx  = (int*)  alloc((size_t)B_ * NK_ * 4);           // 1.3 MB
    float* x0   = (float*)alloc((size_t)B_ * 13 * NK_ * 4);      // 17 MB
    bf16*  y2   = (bf16*) alloc((size_t)B_ * 64 * NK_ * 2);      // 42 MB
    bf16*  y3   = (bf16*) alloc((size_t)B_ * 128 * NK_ * 2);     // 84 MB (reused in-place as x3)
    float* m4   = (float*)alloc((size_t)B_ * 256 * N_ * 4);      // 16.8 MB
    bf16*  w4b  = (bf16*) alloc(256 * 128 * 2);                  // 64 KB
    float* p1   = (float*)alloc((size_t)B_ * NBLK_ * 32 * 4);    // 164 KB
    float* p2   = (float*)alloc((size_t)B_ * NBLK_ * 32 * 4);
    float* p3   = (float*)alloc((size_t)B_ * NBLK_ * 32 * 4);
    float* part4= (float*)alloc(4 * 16 * 2 * 256 * 4);           // 128 KB
    float* a1 = (float*)alloc(B_ * 64 * 4);
    float* s1 = (float*)alloc(B_ * 64 * 4);
    float* a2 = (float*)alloc(B_ * 64 * 4);
    float* s2 = (float*)alloc(B_ * 64 * 4);
    float* a3 = (float*)alloc(B_ * 128 * 4);
    float* s3 = (float*)alloc(B_ * 128 * 4);
    float* a4 = (float*)alloc(B_ * 256 * 4);
    float* s4 = (float*)alloc(B_ * 256 * 4);
    (void)ws_size; (void)in_sizes; (void)n_in; (void)out_size;

    knn_kernel<<<(B_ * N_) / 4, 256, 0, stream>>>(pts, idx);
    w4b_kernel<<<128, 256, 0, stream>>>(W4, w4b);
    feature_kernel<<<(B_ * NK_) / 256, 256, 0, stream>>>(pts, idx, x0);

    stage1_kernel<<<dim3(NBLK_, B_), 256, 0, stream>>>(x0, W1, p1);
    finalize_kernel<64><<<1, 256, 0, stream>>>(p1, g1, bt1, a1, s1);

    stage2_kernel<<<dim3(NBLK_, B_), 256, 0, stream>>>(x0, W1, a1, s1, W2, y2, p2);
    finalize_kernel<64><<<1, 256, 0, stream>>>(p2, g2, bt2, a2, s2);

    stage3_kernel<<<dim3(NBLK_, B_), 256, 0, stream>>>(y2, a2, s2, W3, y3, p3);
    finalize_kernel<128><<<2, 256, 0, stream>>>(p3, g3, bt3, a3, s3);

    prep4_kernel<<<(B_ * 128 * (NK_ / 8)) / 256, 256, 0, stream>>>((unsigned short*)y3, a3, s3);
    conv4_mfma_kernel<<<dim3(N_ / 16, 4, B_), 256, 0, stream>>>((const short*)y3, (const short*)w4b, m4, part4);
    finalize4_kernel<<<4, 256, 0, stream>>>(part4, g4, bt4, a4, s4);

    apply_kernel<<<(B_ * 256 * N_) / 256, 256, 0, stream>>>(m4, a4, s4, out);
}